// Round 1
// baseline (122.415 us; speedup 1.0000x reference)
//
#include <hip/hip_runtime.h>

#define NCLS 10
#define NBLK 1024   // grid size of loss_main; partials are [2*NCLS][NBLK] in d_ws

// Column-major partials in d_ws: partial[c*NBLK + b]
//   c in [0,10)  : per-class sum of (o-t)^2 * m  for block b
//   c in [10,20) : per-class masked count (float) for block b
// Every slot is fully written by loss_main before loss_reduce reads it,
// so the harness's 0xAA poison of d_ws is harmless.
//
// Traversal order, per-thread accumulation order, and the reduction tree are
// IDENTICAL to the previous version -> bit-identical output (absmax 0.0).
// Only change: exact-shape fast path with full unroll + 2-deep load pipeline
// to deepen MLP (3 loads in flight ~450 VALU-cycles ahead of consumption).
__global__ __launch_bounds__(256) void loss_main(const float* __restrict__ outputs,
                                                 const int* __restrict__ targets,
                                                 const int* __restrict__ mask,
                                                 float* __restrict__ partial,
                                                 int n) {
    float sum[NCLS];
    float cnt[NCLS];
#pragma unroll
    for (int c = 0; c < NCLS; ++c) { sum[c] = 0.0f; cnt[c] = 0.0f; }

    const int tid = blockIdx.x * blockDim.x + threadIdx.x;
    const int stride = gridDim.x * blockDim.x;
    const int nv = n >> 2;  // vec4 groups

    const float4* __restrict__ o4 = (const float4*)outputs;
    const int4*   __restrict__ t4 = (const int4*)targets;
    const int4*   __restrict__ m4 = (const int4*)mask;

    auto proc1 = [&](float o, int t, int mk) {
        float m = (mk == 1) ? 1.0f : 0.0f;
        float d = o - (float)t; d = d * d * m;
#pragma unroll
        for (int c = 0; c < NCLS; ++c) {
            bool hit = (t == c);
            sum[c] += hit ? d : 0.0f;
            cnt[c] += hit ? m : 0.0f;
        }
    };
    auto proc4 = [&](const float4& o, const int4& t, const int4& mk) {
        proc1(o.x, t.x, mk.x);
        proc1(o.y, t.y, mk.y);
        proc1(o.z, t.z, mk.z);
        proc1(o.w, t.w, mk.w);
    };

    if (nv == (stride << 3)) {
        // Exact shape (B*H*W = 8,388,608, grid 1024x256): every thread does
        // exactly 8 vec4 groups, tid < stride always. 2-deep rotating pipeline,
        // fully unrolled so all pipeline indices are compile-time static.
        float4 oA = o4[tid],          oB = o4[tid + stride];
        int4   tA = t4[tid],          tB = t4[tid + stride];
        int4   mA = m4[tid],          mB = m4[tid + stride];
#pragma unroll
        for (int k = 0; k < 8; ++k) {
            float4 oN; int4 tN; int4 mN;
            if (k < 6) {
                const int j = tid + (k + 2) * stride;
                oN = o4[j]; tN = t4[j]; mN = m4[j];
            }
            proc4(oA, tA, mA);      // same element order as before -> bit-identical
            oA = oB; tA = tB; mA = mB;
            oB = oN; tB = tN; mB = mN;
        }
    } else {
        // generic fallback (unused at this shape, kept for safety)
        for (int i = tid; i < nv; i += stride) {
            float4 o = o4[i];
            int4   t = t4[i];
            int4   mk = m4[i];
            proc4(o, t, mk);
        }
        // scalar tail (n % 4 != 0)
        for (int i = (nv << 2) + tid; i < n; i += stride) {
            proc1(outputs[i], targets[i], mask[i]);
        }
    }

    // wave-64 butterfly reduction of all 20 accumulators
#pragma unroll
    for (int c = 0; c < NCLS; ++c) {
#pragma unroll
        for (int off = 32; off > 0; off >>= 1) {
            sum[c] += __shfl_xor(sum[c], off, 64);
            cnt[c] += __shfl_xor(cnt[c], off, 64);
        }
    }

    __shared__ float sp[4][2 * NCLS];  // 4 waves per block
    const int lane = threadIdx.x & 63;
    const int wave = threadIdx.x >> 6;
    if (lane == 0) {
#pragma unroll
        for (int c = 0; c < NCLS; ++c) {
            sp[wave][c] = sum[c];
            sp[wave][NCLS + c] = cnt[c];
        }
    }
    __syncthreads();
    if (threadIdx.x < 2 * NCLS) {
        float v = sp[0][threadIdx.x] + sp[1][threadIdx.x] +
                  sp[2][threadIdx.x] + sp[3][threadIdx.x];
        partial[threadIdx.x * NBLK + blockIdx.x] = v;
    }
}

// One block, 16 waves. A column is NBLK=1024 floats = 256 float4s; each of the
// 64 lanes reads 4 float4s (lane, lane+64, lane+128, lane+192) -> 16 floats/lane.
// Wave w reduces columns {w, w+16}; thread 0 finalizes:
//   out[0] = loss, out[1..10] = loss4each, out[11..20] = class_n
__global__ __launch_bounds__(1024) void loss_reduce(const float* __restrict__ partial,
                                                    float* __restrict__ out) {
    __shared__ float col[2 * NCLS];
    const int wave = threadIdx.x >> 6;
    const int lane = threadIdx.x & 63;

#pragma unroll
    for (int k = 0; k < 2; ++k) {
        const int c = wave + k * 16;
        if (c < 2 * NCLS) {
            const float4* p4 = (const float4*)(partial + c * NBLK);
            float v = 0.0f;
#pragma unroll
            for (int j = 0; j < NBLK / 4 / 64; ++j) {   // 4 iterations
                float4 f = p4[lane + j * 64];
                v += (f.x + f.y) + (f.z + f.w);
            }
#pragma unroll
            for (int off = 32; off > 0; off >>= 1) v += __shfl_xor(v, off, 64);
            if (lane == 0) col[c] = v;
        }
    }
    __syncthreads();

    if (threadIdx.x == 0) {
        float loss = 0.0f;
#pragma unroll
        for (int c = 0; c < NCLS; ++c) {
            float s = col[c];
            float nn = col[NCLS + c];
            float l4 = (nn > 0.0f) ? (s / nn) : 0.0f;  // nn>0 => nn>=1, matches max(nn,1)
            out[1 + c] = l4;
            out[11 + c] = nn;
            loss += 0.1f * l4;
        }
        out[0] = loss;
    }
}

extern "C" void kernel_launch(void* const* d_in, const int* in_sizes, int n_in,
                              void* d_out, int out_size, void* d_ws, size_t ws_size,
                              hipStream_t stream) {
    const float* outputs = (const float*)d_in[0];
    const int*   targets = (const int*)d_in[1];
    const int*   mask    = (const int*)d_in[2];
    float* out = (float*)d_out;
    float* partial = (float*)d_ws;   // needs 2*NCLS*NBLK*4 = 80 KB
    const int n = in_sizes[0];

    loss_main<<<NBLK, 256, 0, stream>>>(outputs, targets, mask, partial, n);
    loss_reduce<<<1, 1024, 0, stream>>>(partial, out);
}